// Round 2
// baseline (952.242 us; speedup 1.0000x reference)
//
#include <hip/hip_runtime.h>
#include <cstddef>

// B=4, L=1024 -> ROWS=4096; m=64; Dc=256; Dq=inner=512; H=8; DH=64.
// Restructured (exact in real arithmetic):
//   Qk[r,h,c] = scale * sum_d Q[r,hd] Wk[c,hd];  scores[r,h,m] = sum_c ctx[r,m,c] Qk[r,h,c]
//   CA[r,h,c] = sum_m attn[r,h,m] ctx[r,m,c];    out_inner[r,hd] = sum_c CA[r,h,c] Wv[c,hd]
// Total ~8.6 GFLOP fp32 (vs 137 GFLOP naive K/V projection).

#define NROWS 4096

// K0: WkT[i*256 + c] = Wk[c*512 + i]
__global__ __launch_bounds__(256) void k_transpose(const float* __restrict__ Wk,
                                                   float* __restrict__ WkT) {
  int idx = blockIdx.x * 256 + threadIdx.x;
  int i = idx >> 8, c = idx & 255;
  WkT[idx] = Wk[c * 512 + i];
}

// Generic register-tiled fp32 GEMM. C tile = 64 rows x 64 cols per block, 256 thr, 4x4/thread.
//   cb = blockIdx.x % nCB (col block), rb = blockIdx.x / nCB, h = cb / aCBH (head slice)
//   Ab = A + rb*64*lda + h*aHS          (A row-major, head col-offset aHS)
//   Bb = B + h*bHS + (cb%aCBH)*64       (B row-major ldb)
//   C[row, cb*64 + col] = scale*acc + bias[col_global]
// A chunk (64x64) staged transposed in LDS stride 68 (16B-aligned rows, <=2-way banks on read).
// B read from global: per wave per k one 64B line (4 distinct float4, 16-lane broadcast) -> L1-hot.
__global__ __launch_bounds__(256) void k_gemm(const float* __restrict__ A,
                                              const float* __restrict__ B,
                                              const float* __restrict__ bias,
                                              float* __restrict__ C,
                                              int lda, int ldb, int ldc, int K,
                                              int nCB, int aCBH, int aHS, int bHS,
                                              float scale) {
  __shared__ float As[64 * 68];   // 17 KB, As[k*68 + row]
  int t = threadIdx.x;
  int cb = blockIdx.x % nCB, rb = blockIdx.x / nCB;
  int h = cb / aCBH;
  const float* Ab = A + (size_t)rb * 64 * lda + (size_t)h * aHS;
  const float* Bb = B + (size_t)h * bHS + (size_t)(cb % aCBH) * 64;
  int tr = t & 15, tc = t >> 4;
  float acc[4][4] = {};
  for (int k0 = 0; k0 < K; k0 += 64) {
    __syncthreads();
#pragma unroll
    for (int i = 0; i < 4; ++i) {
      int idx = t + i * 256;            // 0..1023 float4 slots of the 64x64 chunk
      int row = idx >> 4;               // 0..63 (coalesced: 16 consecutive f4 per row)
      int kq = idx & 15;
      float4 v = *(const float4*)(Ab + (size_t)row * lda + k0 + kq * 4);
      As[(kq * 4 + 0) * 68 + row] = v.x;
      As[(kq * 4 + 1) * 68 + row] = v.y;
      As[(kq * 4 + 2) * 68 + row] = v.z;
      As[(kq * 4 + 3) * 68 + row] = v.w;
    }
    __syncthreads();
    const float* Bp = Bb + (size_t)k0 * ldb + tc * 4;
    const float* Ap = As + tr * 4;
#pragma unroll 8
    for (int k = 0; k < 64; ++k) {
      float4 b4 = *(const float4*)(Bp + (size_t)k * ldb);
      float4 a4 = *(const float4*)(Ap + k * 68);
      acc[0][0] = fmaf(a4.x, b4.x, acc[0][0]);
      acc[0][1] = fmaf(a4.x, b4.y, acc[0][1]);
      acc[0][2] = fmaf(a4.x, b4.z, acc[0][2]);
      acc[0][3] = fmaf(a4.x, b4.w, acc[0][3]);
      acc[1][0] = fmaf(a4.y, b4.x, acc[1][0]);
      acc[1][1] = fmaf(a4.y, b4.y, acc[1][1]);
      acc[1][2] = fmaf(a4.y, b4.z, acc[1][2]);
      acc[1][3] = fmaf(a4.y, b4.w, acc[1][3]);
      acc[2][0] = fmaf(a4.z, b4.x, acc[2][0]);
      acc[2][1] = fmaf(a4.z, b4.y, acc[2][1]);
      acc[2][2] = fmaf(a4.z, b4.z, acc[2][2]);
      acc[2][3] = fmaf(a4.z, b4.w, acc[2][3]);
      acc[3][0] = fmaf(a4.w, b4.x, acc[3][0]);
      acc[3][1] = fmaf(a4.w, b4.y, acc[3][1]);
      acc[3][2] = fmaf(a4.w, b4.z, acc[3][2]);
      acc[3][3] = fmaf(a4.w, b4.w, acc[3][3]);
    }
  }
  int colg = cb * 64 + tc * 4;
  float b0 = 0.f, b1 = 0.f, b2 = 0.f, b3 = 0.f;
  if (bias) { b0 = bias[colg]; b1 = bias[colg + 1]; b2 = bias[colg + 2]; b3 = bias[colg + 3]; }
#pragma unroll
  for (int i = 0; i < 4; ++i) {
    float4 o;
    o.x = fmaf(acc[i][0], scale, b0);
    o.y = fmaf(acc[i][1], scale, b1);
    o.z = fmaf(acc[i][2], scale, b2);
    o.w = fmaf(acc[i][3], scale, b3);
    *(float4*)(C + (size_t)(rb * 64 + tr * 4 + i) * ldc + colg) = o;
  }
}

// K3: per-row fused attention. 1 block per (b,l) row. LDS ~44.5 KB -> 3 blocks/CU.
__global__ __launch_bounds__(256) void k_attn(const float* __restrict__ ctx,
                                              const float* __restrict__ Qk,
                                              const float* __restrict__ bias,
                                              const int* __restrict__ mask,
                                              float* __restrict__ CA) {
  __shared__ float ctxs[64 * 132];   // 128-wide c-chunk, stride 132 (16B-aligned, balanced banks)
  __shared__ float qks[2048];
  __shared__ float sc[512];          // normalized attn [h*64+m]
  __shared__ float bs[64];
  __shared__ int   ms[64];
  int t = threadIdx.x;
  int r = blockIdx.x;
  const float* ctxr = ctx + (size_t)r * 16384;

  const float4* q4 = (const float4*)(Qk + (size_t)r * 2048);
  ((float4*)qks)[t]       = q4[t];
  ((float4*)qks)[t + 256] = q4[t + 256];
  if (t < 64) { bs[t] = bias[(size_t)r * 64 + t]; ms[t] = mask[(size_t)r * 64 + t]; }

  int m_ = t & 63, h0 = t >> 6;     // lane->token, wave->heads {h0, h0+4}
  float s0 = 0.f, s1 = 0.f;
  for (int kk = 0; kk < 2; ++kk) {
    __syncthreads();
#pragma unroll
    for (int i = 0; i < 8; ++i) {
      int l = t + i * 256;           // 0..2047 f4 slots
      int m = l >> 5, c4 = l & 31;
      float4 v = *(const float4*)(ctxr + m * 256 + kk * 128 + c4 * 4);
      *(float4*)(ctxs + m * 132 + c4 * 4) = v;
    }
    __syncthreads();
    const float* cp = ctxs + m_ * 132;
    const float* q0 = qks + h0 * 256 + kk * 128;
    const float* q1 = q0 + 1024;
#pragma unroll 8
    for (int c4 = 0; c4 < 32; ++c4) {
      float4 cv = *(const float4*)(cp + c4 * 4);
      float4 qa = *(const float4*)(q0 + c4 * 4);   // wave-uniform -> broadcast
      float4 qb = *(const float4*)(q1 + c4 * 4);
      s0 = fmaf(cv.x, qa.x, s0); s0 = fmaf(cv.y, qa.y, s0);
      s0 = fmaf(cv.z, qa.z, s0); s0 = fmaf(cv.w, qa.w, s0);
      s1 = fmaf(cv.x, qb.x, s1); s1 = fmaf(cv.y, qb.y, s1);
      s1 = fmaf(cv.z, qb.z, s1); s1 = fmaf(cv.w, qb.w, s1);
    }
  }
  bool valid = ms[m_] != 0;
  float b = bs[m_];
  s0 = valid ? s0 + b : -INFINITY;
  s1 = valid ? s1 + b : -INFINITY;
  // per-head softmax over m=64: wave w holds head w (s0) and head w+4 (s1), one token/lane
  float mx0 = s0, mx1 = s1;
#pragma unroll
  for (int o = 32; o > 0; o >>= 1) {
    mx0 = fmaxf(mx0, __shfl_xor(mx0, o, 64));
    mx1 = fmaxf(mx1, __shfl_xor(mx1, o, 64));
  }
  float e0 = __expf(s0 - mx0), e1 = __expf(s1 - mx1);
  float sm0 = e0, sm1 = e1;
#pragma unroll
  for (int o = 32; o > 0; o >>= 1) {
    sm0 += __shfl_xor(sm0, o, 64);
    sm1 += __shfl_xor(sm1, o, 64);
  }
  sc[h0 * 64 + m_]       = e0 / sm0;
  sc[(h0 + 4) * 64 + m_] = e1 / sm1;
  __syncthreads();
  // CA[h,c] = sum_m attn[h,m] ctx[m,c]; lane = c -> coalesced L2-hot re-read
  float acc[8] = {};
#pragma unroll 4
  for (int m = 0; m < 64; ++m) {
    float cv = ctxr[m * 256 + t];
#pragma unroll
    for (int hh = 0; hh < 8; ++hh) acc[hh] = fmaf(sc[hh * 64 + m], cv, acc[hh]);
  }
#pragma unroll
  for (int hh = 0; hh < 8; ++hh) CA[(size_t)r * 2048 + hh * 256 + t] = acc[hh];
}

extern "C" void kernel_launch(void* const* d_in, const int* in_sizes, int n_in,
                              void* d_out, int out_size, void* d_ws, size_t ws_size,
                              hipStream_t stream) {
  const float* x    = (const float*)d_in[0];
  const float* ctx  = (const float*)d_in[1];
  const int*   mask = (const int*)d_in[2];
  const float* bias = (const float*)d_in[3];
  const float* Wq   = (const float*)d_in[4];
  const float* Wk   = (const float*)d_in[5];
  const float* Wv   = (const float*)d_in[6];
  const float* Wo   = (const float*)d_in[7];
  const float* bo   = (const float*)d_in[8];
  float* out = (float*)d_out;

  float* ws  = (float*)d_ws;
  float* WkT = ws;                          // 0.5 MB
  float* Qk  = ws + 131072;                 // 32 MB  (reused as out_inner after K3)
  float* CA  = Qk + (size_t)NROWS * 2048;   // 32 MB
  float* OI  = Qk;                          // out_inner aliases Qk (dead after k_attn)
  float* Q   = out;                         // Q lives in d_out (dead after K2)

  hipLaunchKernelGGL(k_transpose, dim3(512), dim3(256), 0, stream, Wk, WkT);
  // K1: Q = x @ Wq                  [4096x512] = [4096x512][512x512]
  hipLaunchKernelGGL(k_gemm, dim3(512), dim3(256), 0, stream,
                     x, Wq, (const float*)nullptr, Q, 512, 512, 512, 512, 8, 8, 0, 0, 1.0f);
  // K2: Qk[r, h*256+c] = 0.125 * sum_d Q[r,h*64+d] WkT[(h*64+d)*256+c]   (per-head K=64)
  hipLaunchKernelGGL(k_gemm, dim3(2048), dim3(256), 0, stream,
                     Q, WkT, (const float*)nullptr, Qk, 512, 256, 2048, 64, 32, 4, 64, 16384, 0.125f);
  // K3: fused scores+softmax+ctx-weighting
  hipLaunchKernelGGL(k_attn, dim3(4096), dim3(256), 0, stream, ctx, Qk, bias, mask, CA);
  // K4: OI[r, h*64+d] = sum_c CA[r,h*256+c] Wv[c*512 + h*64+d]   (per-head A slice, K=256)
  hipLaunchKernelGGL(k_gemm, dim3(512), dim3(256), 0, stream,
                     CA, Wv, (const float*)nullptr, OI, 2048, 512, 512, 256, 8, 1, 256, 64, 1.0f);
  // K5: out = OI @ Wo + bo
  hipLaunchKernelGGL(k_gemm, dim3(512), dim3(256), 0, stream,
                     OI, Wo, bo, out, 512, 512, 512, 512, 8, 8, 0, 0, 1.0f);
}

// Round 3
// 561.449 us; speedup vs baseline: 1.6960x; 1.6960x over previous
//
#include <hip/hip_runtime.h>
#include <cstddef>

// B=4, L=1024 -> ROWS=4096; m=64; Dc=256; Dq=inner=512; H=8; DH=64.
// Restructured (exact in real arithmetic):
//   Qk[r,h,c] = scale * sum_d Q[r,hd] Wk[c,hd];  scores[r,h,m] = sum_c ctx[r,m,c] Qk[r,h,c]
//   CA[r,h,c] = sum_m attn[r,h,m] ctx[r,m,c];    out_inner[r,hd] = sum_c CA[r,h,c] Wv[c,hd]
// Total ~8.6 GFLOP fp32 (vs 137 GFLOP naive K/V projection).

#define NROWS 4096

// K0: WkT[i*256 + c] = Wk[c*512 + i]
__global__ __launch_bounds__(256) void k_transpose(const float* __restrict__ Wk,
                                                   float* __restrict__ WkT) {
  int idx = blockIdx.x * 256 + threadIdx.x;
  int i = idx >> 8, c = idx & 255;
  WkT[idx] = Wk[c * 512 + i];
}

// Register-tiled fp32 GEMM, BOTH operands staged in LDS, register-prefetch pipeline.
// C tile 64x64/block, 256 thr, 4x4/thread, K chunk 64.
// As transposed [k][row] stride 68 with k-quad swizzle col=(row+4*((k>>2)&7))&63:
//   - staging writes spread 2-way across banks (free), reads stay 16B-aligned ds_read_b128.
// Bs row-major [k][col] stride 68: reads are 16-lane broadcasts, writes at b128 floor rate.
// Inner loop: 2x ds_read_b128 + 16 FMA -> VALU-bound (~32 cyc VALU vs ~14 cyc LDS per wave-iter).
__global__ __launch_bounds__(256) void k_gemm(const float* __restrict__ A,
                                              const float* __restrict__ B,
                                              const float* __restrict__ bias,
                                              float* __restrict__ C,
                                              int lda, int ldb, int ldc, int K,
                                              int nCB, int aCBH, int aHS, int bHS,
                                              float scale) {
  __shared__ __align__(16) float As[64 * 68];   // 17 KB
  __shared__ __align__(16) float Bs[64 * 68];   // 17 KB
  int t = threadIdx.x;
  int cb = blockIdx.x % nCB, rb = blockIdx.x / nCB;
  int h = cb / aCBH;
  const float* Ab = A + (size_t)rb * 64 * lda + (size_t)h * aHS;
  const float* Bb = B + (size_t)h * bHS + (size_t)(cb % aCBH) * 64;
  int tr = t & 15, tc = t >> 4;
  float acc[4][4] = {};
  float4 pa[4], pb[4];

  // prefetch chunk 0
#pragma unroll
  for (int i = 0; i < 4; ++i) {
    int idx = t + i * 256;            // 0..1023
    int r_ = idx >> 4, q_ = idx & 15; // tile row / float4-quad along k (or col for B)
    pa[i] = *(const float4*)(Ab + (size_t)r_ * lda + q_ * 4);
    pb[i] = *(const float4*)(Bb + (size_t)r_ * ldb + q_ * 4);
  }

  for (int k0 = 0; k0 < K; k0 += 64) {
    __syncthreads();
#pragma unroll
    for (int i = 0; i < 4; ++i) {
      int idx = t + i * 256;
      int r_ = idx >> 4, q_ = idx & 15;
      int col = (r_ + ((q_ & 7) << 2)) & 63;       // swizzled transpose store
      As[(q_ * 4 + 0) * 68 + col] = pa[i].x;
      As[(q_ * 4 + 1) * 68 + col] = pa[i].y;
      As[(q_ * 4 + 2) * 68 + col] = pa[i].z;
      As[(q_ * 4 + 3) * 68 + col] = pa[i].w;
      *(float4*)(Bs + r_ * 68 + q_ * 4) = pb[i];
    }
    __syncthreads();
    if (k0 + 64 < K) {                 // prefetch next chunk; waitcnt lands next iteration
#pragma unroll
      for (int i = 0; i < 4; ++i) {
        int idx = t + i * 256;
        int r_ = idx >> 4, q_ = idx & 15;
        pa[i] = *(const float4*)(Ab + (size_t)r_ * lda + (k0 + 64) + q_ * 4);
        pb[i] = *(const float4*)(Bb + (size_t)(k0 + 64 + r_) * ldb + q_ * 4);
      }
    }
#pragma unroll 8
    for (int k = 0; k < 64; ++k) {
      float4 a4 = *(const float4*)(As + k * 68 + (((tr << 2) + (((k >> 2) & 7) << 2)) & 63));
      float4 b4 = *(const float4*)(Bs + k * 68 + (tc << 2));
      acc[0][0] = fmaf(a4.x, b4.x, acc[0][0]);
      acc[0][1] = fmaf(a4.x, b4.y, acc[0][1]);
      acc[0][2] = fmaf(a4.x, b4.z, acc[0][2]);
      acc[0][3] = fmaf(a4.x, b4.w, acc[0][3]);
      acc[1][0] = fmaf(a4.y, b4.x, acc[1][0]);
      acc[1][1] = fmaf(a4.y, b4.y, acc[1][1]);
      acc[1][2] = fmaf(a4.y, b4.z, acc[1][2]);
      acc[1][3] = fmaf(a4.y, b4.w, acc[1][3]);
      acc[2][0] = fmaf(a4.z, b4.x, acc[2][0]);
      acc[2][1] = fmaf(a4.z, b4.y, acc[2][1]);
      acc[2][2] = fmaf(a4.z, b4.z, acc[2][2]);
      acc[2][3] = fmaf(a4.z, b4.w, acc[2][3]);
      acc[3][0] = fmaf(a4.w, b4.x, acc[3][0]);
      acc[3][1] = fmaf(a4.w, b4.y, acc[3][1]);
      acc[3][2] = fmaf(a4.w, b4.z, acc[3][2]);
      acc[3][3] = fmaf(a4.w, b4.w, acc[3][3]);
    }
  }
  int colg = cb * 64 + tc * 4;
  float b0 = 0.f, b1 = 0.f, b2 = 0.f, b3 = 0.f;
  if (bias) { b0 = bias[colg]; b1 = bias[colg + 1]; b2 = bias[colg + 2]; b3 = bias[colg + 3]; }
#pragma unroll
  for (int i = 0; i < 4; ++i) {
    float4 o;
    o.x = fmaf(acc[i][0], scale, b0);
    o.y = fmaf(acc[i][1], scale, b1);
    o.z = fmaf(acc[i][2], scale, b2);
    o.w = fmaf(acc[i][3], scale, b3);
    *(float4*)(C + (size_t)(rb * 64 + tr * 4 + i) * ldc + colg) = o;
  }
}

// K3: per-row fused attention. 1 block per (b,l) row. LDS ~44.5 KB -> 3 blocks/CU.
__global__ __launch_bounds__(256) void k_attn(const float* __restrict__ ctx,
                                              const float* __restrict__ Qk,
                                              const float* __restrict__ bias,
                                              const int* __restrict__ mask,
                                              float* __restrict__ CA) {
  __shared__ float ctxs[64 * 132];
  __shared__ float qks[2048];
  __shared__ float sc[512];
  __shared__ float bs[64];
  __shared__ int   ms[64];
  int t = threadIdx.x;
  int r = blockIdx.x;
  const float* ctxr = ctx + (size_t)r * 16384;

  const float4* q4 = (const float4*)(Qk + (size_t)r * 2048);
  ((float4*)qks)[t]       = q4[t];
  ((float4*)qks)[t + 256] = q4[t + 256];
  if (t < 64) { bs[t] = bias[(size_t)r * 64 + t]; ms[t] = mask[(size_t)r * 64 + t]; }

  int m_ = t & 63, h0 = t >> 6;
  float s0 = 0.f, s1 = 0.f;
  for (int kk = 0; kk < 2; ++kk) {
    __syncthreads();
#pragma unroll
    for (int i = 0; i < 8; ++i) {
      int l = t + i * 256;
      int m = l >> 5, c4 = l & 31;
      float4 v = *(const float4*)(ctxr + m * 256 + kk * 128 + c4 * 4);
      *(float4*)(ctxs + m * 132 + c4 * 4) = v;
    }
    __syncthreads();
    const float* cp = ctxs + m_ * 132;
    const float* q0 = qks + h0 * 256 + kk * 128;
    const float* q1 = q0 + 1024;
#pragma unroll 8
    for (int c4 = 0; c4 < 32; ++c4) {
      float4 cv = *(const float4*)(cp + c4 * 4);
      float4 qa = *(const float4*)(q0 + c4 * 4);
      float4 qb = *(const float4*)(q1 + c4 * 4);
      s0 = fmaf(cv.x, qa.x, s0); s0 = fmaf(cv.y, qa.y, s0);
      s0 = fmaf(cv.z, qa.z, s0); s0 = fmaf(cv.w, qa.w, s0);
      s1 = fmaf(cv.x, qb.x, s1); s1 = fmaf(cv.y, qb.y, s1);
      s1 = fmaf(cv.z, qb.z, s1); s1 = fmaf(cv.w, qb.w, s1);
    }
  }
  bool valid = ms[m_] != 0;
  float b = bs[m_];
  s0 = valid ? s0 + b : -INFINITY;
  s1 = valid ? s1 + b : -INFINITY;
  float mx0 = s0, mx1 = s1;
#pragma unroll
  for (int o = 32; o > 0; o >>= 1) {
    mx0 = fmaxf(mx0, __shfl_xor(mx0, o, 64));
    mx1 = fmaxf(mx1, __shfl_xor(mx1, o, 64));
  }
  float e0 = __expf(s0 - mx0), e1 = __expf(s1 - mx1);
  float sm0 = e0, sm1 = e1;
#pragma unroll
  for (int o = 32; o > 0; o >>= 1) {
    sm0 += __shfl_xor(sm0, o, 64);
    sm1 += __shfl_xor(sm1, o, 64);
  }
  sc[h0 * 64 + m_]       = e0 / sm0;
  sc[(h0 + 4) * 64 + m_] = e1 / sm1;
  __syncthreads();
  float acc[8] = {};
#pragma unroll 4
  for (int m = 0; m < 64; ++m) {
    float cv = ctxr[m * 256 + t];
#pragma unroll
    for (int hh = 0; hh < 8; ++hh) acc[hh] = fmaf(sc[hh * 64 + m], cv, acc[hh]);
  }
#pragma unroll
  for (int hh = 0; hh < 8; ++hh) CA[(size_t)r * 2048 + hh * 256 + t] = acc[hh];
}

extern "C" void kernel_launch(void* const* d_in, const int* in_sizes, int n_in,
                              void* d_out, int out_size, void* d_ws, size_t ws_size,
                              hipStream_t stream) {
  const float* x    = (const float*)d_in[0];
  const float* ctx  = (const float*)d_in[1];
  const int*   mask = (const int*)d_in[2];
  const float* bias = (const float*)d_in[3];
  const float* Wq   = (const float*)d_in[4];
  const float* Wk   = (const float*)d_in[5];
  const float* Wv   = (const float*)d_in[6];
  const float* Wo   = (const float*)d_in[7];
  const float* bo   = (const float*)d_in[8];
  float* out = (float*)d_out;

  float* ws  = (float*)d_ws;
  float* WkT = ws;                          // 0.5 MB
  float* Qk  = ws + 131072;                 // 32 MB
  float* CA  = Qk + (size_t)NROWS * 2048;   // 32 MB
  float* OI  = Qk;                          // out_inner aliases Qk (dead after k_attn)
  float* Q   = out;                         // Q lives in d_out (dead after K2)

  hipLaunchKernelGGL(k_transpose, dim3(512), dim3(256), 0, stream, Wk, WkT);
  // K1: Q = x @ Wq
  hipLaunchKernelGGL(k_gemm, dim3(512), dim3(256), 0, stream,
                     x, Wq, (const float*)nullptr, Q, 512, 512, 512, 512, 8, 8, 0, 0, 1.0f);
  // K2: Qk[r, h*256+c] = 0.125 * sum_d Q[r,h*64+d] WkT[(h*64+d)*256+c]
  hipLaunchKernelGGL(k_gemm, dim3(2048), dim3(256), 0, stream,
                     Q, WkT, (const float*)nullptr, Qk, 512, 256, 2048, 64, 32, 4, 64, 16384, 0.125f);
  // K3: fused scores+softmax+ctx-weighting
  hipLaunchKernelGGL(k_attn, dim3(4096), dim3(256), 0, stream, ctx, Qk, bias, mask, CA);
  // K4: OI[r, h*64+d] = sum_c CA[r,h*256+c] Wv[c*512 + h*64+d]
  hipLaunchKernelGGL(k_gemm, dim3(512), dim3(256), 0, stream,
                     CA, Wv, (const float*)nullptr, OI, 2048, 512, 512, 256, 8, 1, 256, 64, 1.0f);
  // K5: out = OI @ Wo + bo
  hipLaunchKernelGGL(k_gemm, dim3(512), dim3(256), 0, stream,
                     OI, Wo, bo, out, 512, 512, 512, 512, 8, 8, 0, 0, 1.0f);
}

// Round 4
// 485.258 us; speedup vs baseline: 1.9623x; 1.1570x over previous
//
#include <hip/hip_runtime.h>
#include <cstddef>

// B=4, L=1024 -> ROWS=4096; m=64; Dc=256; Dq=inner=512; H=8; DH=64.
// Restructured (exact in real arithmetic, bf16 inputs to MFMA):
//   Qk[r,h,c]  = 0.125 * sum_d Q[r,hd] Wk[c,hd]          (Q = x@Wq)
//   scores     = ctx . Qk ; softmax ; CA[r,h,c] = sum_m attn*ctx
//   out[r,o]   = sum_{h,c} CA[r,h,c] * Wvo[h,c,o] + bo,  Wvo = Wv_h @ Wo_h (precomputed)
// ~11 GFLOP total at MFMA rates + 300 MB HBM (ctx-dominated).

typedef __attribute__((ext_vector_type(8))) short short8;   // 8 bf16 fragment (4 VGPRs)
typedef __attribute__((ext_vector_type(4))) float float4v;

__device__ __forceinline__ short f2bf(float f) {   // fp32 -> bf16, round-nearest-even
  unsigned u = __float_as_uint(f);
  return (short)((u + 0x7fffu + ((u >> 16) & 1u)) >> 16);
}

// Convert x, Wk, Wv to bf16 (straight layout). 2304 blocks x 256 thr x 4 elems.
__global__ __launch_bounds__(256) void k_cvt(const float* __restrict__ x,
                                             const float* __restrict__ Wk,
                                             const float* __restrict__ Wv,
                                             short* __restrict__ xb,
                                             short* __restrict__ Wkb,
                                             short* __restrict__ Wvb) {
  size_t i4 = ((size_t)blockIdx.x * 256 + threadIdx.x) * 4;
  const float* src; short* dst; size_t off;
  if (i4 < 2097152)       { src = x;  dst = xb;  off = i4; }
  else if (i4 < 2228224)  { src = Wk; dst = Wkb; off = i4 - 2097152; }
  else                    { src = Wv; dst = Wvb; off = i4 - 2228224; }
  float4 v = *(const float4*)(src + off);
  short4 o; o.x = f2bf(v.x); o.y = f2bf(v.y); o.z = f2bf(v.z); o.w = f2bf(v.w);
  *(short4*)(dst + off) = o;
}

// Transpose-convert 512x512 fp32 -> bf16: out[n*512+k] = in[k*512+n]. 1024 blocks.
__global__ __launch_bounds__(256) void k_tcvt(const float* __restrict__ in,
                                              short* __restrict__ out) {
  int id = blockIdx.x * 256 + threadIdx.x;
  int k = id >> 9, n = id & 511;
  out[(size_t)n * 512 + k] = f2bf(in[(size_t)k * 512 + n]);
}

// Generic bf16 MFMA GEMM: C[m0+.., n0+..] = scale * A(m,k) x Bt(n,k) + bias.
// 128x128 block tile, 4 waves (2x2), each wave 64x64 = 4x4 MFMA tiles, BK=64.
// Head plumbing: hb = n0>>bShift;  A k-offset += hb*crossAK;
//                Bt row base = (n0&bMask)*ldb + hb*bHS.
// Fragment layouts (verified m89/m91/m120): A/B lane: idx=lane&15, k=(lane>>4)*8+j;
//                                           C/D: col=lane&15, row=(lane>>4)*4+reg.
__global__ __launch_bounds__(256) void k_mm(const short* __restrict__ A,
                                            const short* __restrict__ Bt,
                                            const float* __restrict__ bias,
                                            void* __restrict__ C,
                                            int lda, int ldb, int ldc, int K,
                                            int bShift, int bMask, int bHS, int crossAK,
                                            float scale, int storeBF16) {
  __shared__ short As[128 * 72];   // [row m][k], stride 72 (144B: 16B-aligned, 2-way banks)
  __shared__ short Bs[128 * 72];   // [row n][k]
  int t = threadIdx.x;
  int n0 = blockIdx.x * 128, m0 = blockIdx.y * 128;
  int hb = n0 >> bShift;
  const short* aBase = A + (size_t)m0 * lda + (size_t)hb * crossAK;
  const short* bBase = Bt + (size_t)(n0 & bMask) * ldb + (size_t)hb * bHS;
  int w = t >> 6, l = t & 63;
  int wm = w & 1, wn = w >> 1;
  int li = l & 15, kq = l >> 4;
  float4v acc[4][4];
#pragma unroll
  for (int i = 0; i < 4; ++i)
#pragma unroll
    for (int j = 0; j < 4; ++j) acc[i][j] = (float4v){0.f, 0.f, 0.f, 0.f};

  for (int k0 = 0; k0 < K; k0 += 64) {
    __syncthreads();
#pragma unroll
    for (int p = 0; p < 4; ++p) {
      int i = p * 256 + t, row = i >> 3, kq8 = i & 7;
      *(uint4*)&As[row * 72 + kq8 * 8] = *(const uint4*)(aBase + (size_t)row * lda + k0 + kq8 * 8);
      *(uint4*)&Bs[row * 72 + kq8 * 8] = *(const uint4*)(bBase + (size_t)row * ldb + k0 + kq8 * 8);
    }
    __syncthreads();
#pragma unroll
    for (int kk = 0; kk < 2; ++kk) {
      short8 af[4], bfr[4];
#pragma unroll
      for (int i = 0; i < 4; ++i) {
        af[i]  = *(const short8*)&As[(wm * 64 + i * 16 + li) * 72 + kk * 32 + kq * 8];
        bfr[i] = *(const short8*)&Bs[(wn * 64 + i * 16 + li) * 72 + kk * 32 + kq * 8];
      }
#pragma unroll
      for (int mi = 0; mi < 4; ++mi)
#pragma unroll
        for (int ni = 0; ni < 4; ++ni)
          acc[mi][ni] = __builtin_amdgcn_mfma_f32_16x16x32_bf16(af[mi], bfr[ni], acc[mi][ni], 0, 0, 0);
    }
  }
#pragma unroll
  for (int ni = 0; ni < 4; ++ni) {
    int col = n0 + wn * 64 + ni * 16 + li;
    float bv = bias ? bias[col] : 0.f;
#pragma unroll
    for (int mi = 0; mi < 4; ++mi)
#pragma unroll
      for (int r = 0; r < 4; ++r) {
        int row = m0 + wm * 64 + mi * 16 + kq * 4 + r;
        float v = fmaf(acc[mi][ni][r], scale, bv);
        if (storeBF16) ((short*)C)[(size_t)row * ldc + col] = f2bf(v);
        else           ((float*)C)[(size_t)row * ldc + col] = v;
      }
  }
}

// Fused per-row attention (fp32 math). 1 block / (b,l) row. LDS ~44.5 KB -> 3 blocks/CU.
// CA written as bf16 for the final MFMA GEMM.
__global__ __launch_bounds__(256) void k_attn(const float* __restrict__ ctx,
                                              const float* __restrict__ Qk,
                                              const float* __restrict__ bias,
                                              const int* __restrict__ mask,
                                              short* __restrict__ CA) {
  __shared__ float ctxs[64 * 132];
  __shared__ float qks[2048];
  __shared__ float sc[512];          // attn weights, [m][h] layout -> b128 broadcast reads
  __shared__ float bs[64];
  __shared__ int   ms[64];
  int t = threadIdx.x;
  int r = blockIdx.x;
  const float* ctxr = ctx + (size_t)r * 16384;

  const float4* q4 = (const float4*)(Qk + (size_t)r * 2048);
  ((float4*)qks)[t]       = q4[t];
  ((float4*)qks)[t + 256] = q4[t + 256];
  if (t < 64) { bs[t] = bias[(size_t)r * 64 + t]; ms[t] = mask[(size_t)r * 64 + t]; }

  int m_ = t & 63, h0 = t >> 6;
  float s0 = 0.f, s1 = 0.f;
  for (int kk = 0; kk < 2; ++kk) {
    __syncthreads();
#pragma unroll
    for (int i = 0; i < 8; ++i) {
      int l = t + i * 256;
      int m = l >> 5, c4 = l & 31;
      float4 v = *(const float4*)(ctxr + m * 256 + kk * 128 + c4 * 4);
      *(float4*)(ctxs + m * 132 + c4 * 4) = v;
    }
    __syncthreads();
    const float* cp = ctxs + m_ * 132;
    const float* q0 = qks + h0 * 256 + kk * 128;
    const float* q1 = q0 + 1024;
#pragma unroll 8
    for (int c4 = 0; c4 < 32; ++c4) {
      float4 cv = *(const float4*)(cp + c4 * 4);
      float4 qa = *(const float4*)(q0 + c4 * 4);
      float4 qb = *(const float4*)(q1 + c4 * 4);
      s0 = fmaf(cv.x, qa.x, s0); s0 = fmaf(cv.y, qa.y, s0);
      s0 = fmaf(cv.z, qa.z, s0); s0 = fmaf(cv.w, qa.w, s0);
      s1 = fmaf(cv.x, qb.x, s1); s1 = fmaf(cv.y, qb.y, s1);
      s1 = fmaf(cv.z, qb.z, s1); s1 = fmaf(cv.w, qb.w, s1);
    }
  }
  bool valid = ms[m_] != 0;
  float b = bs[m_];
  s0 = valid ? s0 + b : -INFINITY;
  s1 = valid ? s1 + b : -INFINITY;
  float mx0 = s0, mx1 = s1;
#pragma unroll
  for (int o = 32; o > 0; o >>= 1) {
    mx0 = fmaxf(mx0, __shfl_xor(mx0, o, 64));
    mx1 = fmaxf(mx1, __shfl_xor(mx1, o, 64));
  }
  float e0 = __expf(s0 - mx0), e1 = __expf(s1 - mx1);
  float sm0 = e0, sm1 = e1;
#pragma unroll
  for (int o = 32; o > 0; o >>= 1) {
    sm0 += __shfl_xor(sm0, o, 64);
    sm1 += __shfl_xor(sm1, o, 64);
  }
  sc[m_ * 8 + h0]     = e0 / sm0;
  sc[m_ * 8 + h0 + 4] = e1 / sm1;
  __syncthreads();
  // CA[h,c] = sum_m attn[h,m] ctx[m,c]; lane = c (coalesced L2-hot re-read)
  float acc[8] = {};
#pragma unroll 4
  for (int m = 0; m < 64; ++m) {
    float cv = ctxr[m * 256 + t];
    float4 w0 = *(const float4*)&sc[m * 8];       // wave-uniform b128 broadcast
    float4 w1 = *(const float4*)&sc[m * 8 + 4];
    acc[0] = fmaf(w0.x, cv, acc[0]); acc[1] = fmaf(w0.y, cv, acc[1]);
    acc[2] = fmaf(w0.z, cv, acc[2]); acc[3] = fmaf(w0.w, cv, acc[3]);
    acc[4] = fmaf(w1.x, cv, acc[4]); acc[5] = fmaf(w1.y, cv, acc[5]);
    acc[6] = fmaf(w1.z, cv, acc[6]); acc[7] = fmaf(w1.w, cv, acc[7]);
  }
  short* car = CA + (size_t)r * 2048;
#pragma unroll
  for (int hh = 0; hh < 8; ++hh) car[hh * 256 + t] = f2bf(acc[hh]);
}

extern "C" void kernel_launch(void* const* d_in, const int* in_sizes, int n_in,
                              void* d_out, int out_size, void* d_ws, size_t ws_size,
                              hipStream_t stream) {
  const float* x    = (const float*)d_in[0];
  const float* ctx  = (const float*)d_in[1];
  const int*   mask = (const int*)d_in[2];
  const float* bias = (const float*)d_in[3];
  const float* Wq   = (const float*)d_in[4];
  const float* Wk   = (const float*)d_in[5];
  const float* Wv   = (const float*)d_in[6];
  const float* Wo   = (const float*)d_in[7];
  const float* bo   = (const float*)d_in[8];
  float* out = (float*)d_out;

  char* ws = (char*)d_ws;
  short* xb    = (short*)(ws);                       // 4 MB   [4096x512]
  short* Qb    = (short*)(ws + (4u << 20));          // 4 MB   [4096x512]
  float* Qk    = (float*)(ws + (8u << 20));          // 32 MB  [4096x2048] fp32
  short* CAb   = (short*)(ws + (40u << 20));         // 16 MB  [4096x2048]
  short* WqTb  = (short*)(ws + (56u << 20));         // 512 KB [512x512] (n,k)
  short* WoTb  = (short*)(ws + (56u << 20) + (512u << 10));   // 512 KB [512x512] (o,hd)
  short* Wkb   = (short*)(ws + (57u << 20));         // 256 KB [256x512] straight
  short* Wvb   = (short*)(ws + (57u << 20) + (256u << 10));   // 256 KB [256x512] straight
  short* WvoTb = (short*)(ws + (58u << 20));         // 2 MB   [512x2048]: [o][h*256+c]

  // converts
  hipLaunchKernelGGL(k_cvt,  dim3(2304), dim3(256), 0, stream, x, Wk, Wv, xb, Wkb, Wvb);
  hipLaunchKernelGGL(k_tcvt, dim3(1024), dim3(256), 0, stream, Wq, WqTb);
  hipLaunchKernelGGL(k_tcvt, dim3(1024), dim3(256), 0, stream, Wo, WoTb);
  // prep: WvoT[o, h*256+c] = sum_d WoT[o, h*64+d] * Wv[c, h*64+d]   (K=64, head on N side)
  hipLaunchKernelGGL(k_mm, dim3(16, 4), dim3(256), 0, stream,
                     WoTb, Wvb, (const float*)nullptr, WvoTb,
                     512, 512, 2048, 64, 8, 255, 64, 64, 1.0f, 1);
  // K1: Qb = xb @ WqT^T   (M=4096,N=512,K=512)
  hipLaunchKernelGGL(k_mm, dim3(4, 32), dim3(256), 0, stream,
                     xb, WqTb, (const float*)nullptr, Qb,
                     512, 512, 512, 512, 31, 0x7fffffff, 0, 0, 1.0f, 1);
  // K2: Qk[r, h*256+c] = 0.125 * sum_d Qb[r,h*64+d] Wk[c,h*64+d]   (K=64 per head)
  hipLaunchKernelGGL(k_mm, dim3(16, 32), dim3(256), 0, stream,
                     Qb, Wkb, (const float*)nullptr, Qk,
                     512, 512, 2048, 64, 8, 255, 64, 64, 0.125f, 0);
  // attention
  hipLaunchKernelGGL(k_attn, dim3(4096), dim3(256), 0, stream, ctx, Qk, bias, mask, CAb);
  // final: out = CAb @ WvoT^T + bo   (M=4096,N=512,K=2048)
  hipLaunchKernelGGL(k_mm, dim3(4, 32), dim3(256), 0, stream,
                     CAb, WvoTb, bo, out,
                     2048, 2048, 512, 2048, 31, 0x7fffffff, 0, 0, 1.0f, 0);
}